// Round 15
// baseline (334.841 us; speedup 1.0000x reference)
//
#include <hip/hip_runtime.h>
#include <hip/hip_bf16.h>
#include <stdint.h>

#define B_ 4
#define H_ 16
#define L_ 2048
#define D_ 64
#define BH (B_ * H_)
#define NT (BH * 32)   // 64x64 tiles per tensor = 2048
#define MB_ 2048       // mask-pack blocks
#define TILE_BYTES ((size_t)NT * 4096 * 2)   // 16.8 MB per bf16 tensor image

typedef __attribute__((ext_vector_type(8))) short short8;
typedef __attribute__((ext_vector_type(4))) float f32x4;

__device__ __forceinline__ short b16(float f) {
  __hip_bfloat16 h = __float2bfloat16(f);
  return __builtin_bit_cast(short, h);
}
__device__ __forceinline__ unsigned int pkbf16(float lo, float hi) {
  return (unsigned int)(unsigned short)b16(lo) |
         ((unsigned int)(unsigned short)b16(hi) << 16);
}

// ================= prepass: K->bf16, V->transposed bf16, mask->bits =================
// blocks [0,NT):        K fp32 -> Kt bf16 (elementwise)
// blocks [NT,2NT):      V fp32 -> Vt bf16 [bh][d][k] (transpose)
// blocks [2NT,2NT+MB_): mask int32 -> bit mask (1 bit per element, dword-packed)
__global__ __launch_bounds__(256) void prep14_kernel(const float* __restrict__ K,
                                                     const float* __restrict__ V,
                                                     const int* __restrict__ M,
                                                     unsigned short* __restrict__ Kt,
                                                     unsigned short* __restrict__ Vt,
                                                     unsigned int* __restrict__ Mb) {
  __shared__ unsigned short lds[64 * 68];
  int bid = blockIdx.x;
  int t   = threadIdx.x;
  if (bid < NT) {
    const float* src = K + (size_t)bid * 4096;
    unsigned short* dst = Kt + (size_t)bid * 4096;
#pragma unroll
    for (int i = 0; i < 4; ++i) {
      int f4 = i * 256 + t;
      float4 v = *reinterpret_cast<const float4*>(src + f4 * 4);
      ushort4 u;
      u.x = (unsigned short)b16(v.x);
      u.y = (unsigned short)b16(v.y);
      u.z = (unsigned short)b16(v.z);
      u.w = (unsigned short)b16(v.w);
      *reinterpret_cast<ushort4*>(dst + f4 * 4) = u;
    }
  } else if (bid < 2 * NT) {
    bid -= NT;
    int bh = bid >> 5;
    int kt = bid & 31;
    const float* vsrc = V + ((size_t)bh * L_ + (size_t)kt * 64) * D_;
#pragma unroll
    for (int i = 0; i < 4; ++i) {
      int f4  = i * 256 + t;
      int row = f4 >> 4;
      int c4  = (f4 & 15) << 2;
      float4 v = *reinterpret_cast<const float4*>(vsrc + row * D_ + c4);
      ushort4 u;
      u.x = (unsigned short)b16(v.x);
      u.y = (unsigned short)b16(v.y);
      u.z = (unsigned short)b16(v.z);
      u.w = (unsigned short)b16(v.w);
      *reinterpret_cast<ushort4*>(&lds[row * 68 + c4]) = u;
    }
    __syncthreads();
    unsigned short* dst = Vt + (size_t)bh * D_ * L_ + (size_t)kt * 64;
#pragma unroll
    for (int i = 0; i < 8; ++i) {
      int c  = i * 256 + t;
      int d  = c >> 5;
      int k2 = (c & 31) * 2;
      unsigned int lo = lds[(k2 + 0) * 68 + d];
      unsigned int hi = lds[(k2 + 1) * 68 + d];
      *reinterpret_cast<unsigned int*>(dst + d * L_ + k2) = lo | (hi << 16);
    }
  } else {
    // bit-pack: each thread folds 32 consecutive ints into one dword
    int bid2 = bid - 2 * NT;                       // 0..MB_-1
    const int* src = M + (size_t)bid2 * 8192;      // 8192 ints per block
    unsigned int* dst = Mb + (size_t)bid2 * 256;   // 256 dwords per block
    const int* ts = src + t * 32;
    unsigned int pk = 0;
#pragma unroll
    for (int j = 0; j < 8; ++j) {
      int4 v = *reinterpret_cast<const int4*>(ts + j * 4);
      pk |= (v.x ? 1u : 0u) << (j * 4 + 0);
      pk |= (v.y ? 1u : 0u) << (j * 4 + 1);
      pk |= (v.z ? 1u : 0u) << (j * 4 + 2);
      pk |= (v.w ? 1u : 0u) << (j * 4 + 3);
    }
    dst[t] = pk;
  }
}

// ================= attn: R11 structure, bit mask =================
__global__ __launch_bounds__(256, 4) void attn14_kernel(
    const float* __restrict__ Q, const unsigned short* __restrict__ Kt,
    const unsigned int* __restrict__ Mb, const unsigned short* __restrict__ Vt,
    float* __restrict__ O, float* __restrict__ A) {
  __shared__ unsigned short Kl[2][4096];
  __shared__ unsigned short Vl[2][4096];

  // XCD-aware decode (proven mapping)
  int wg  = blockIdx.x;
  int xcd = wg & 7;
  int j   = wg >> 3;
  int g   = xcd * 16 + (j & 15);
  int b   = g >> 5;
  int qt  = g & 31;
  int h   = j >> 4;
  int bh  = b * 16 + h;

  int t    = threadIdx.x;
  int lane = t & 63;
  int w    = t >> 6;
  int lr   = lane & 15;
  int lg   = lane >> 4;
  int qrow0 = qt * 64 + w * 16;

  // Q fragments (B-operand), temperature folded
  short8 qf[2];
  {
    const float* qb = Q + ((size_t)bh * L_ + qrow0 + lr) * D_;
#pragma unroll
    for (int ks = 0; ks < 2; ++ks) {
      const float4* p = reinterpret_cast<const float4*>(qb + ks * 32 + lg * 8);
      float4 a = p[0], c = p[1];
      qf[ks] = (short8){b16(a.x * 0.125f), b16(a.y * 0.125f), b16(a.z * 0.125f), b16(a.w * 0.125f),
                        b16(c.x * 0.125f), b16(c.y * 0.125f), b16(c.z * 0.125f), b16(c.w * 0.125f)};
    }
  }

  f32x4 o[4] = {};
  const unsigned int* mbase = Mb + (size_t)b * L_ * 64;   // 64 dwords per row
  float* abase = A + (size_t)bh * L_ * L_;
  const unsigned short* ktb = Kt + (size_t)bh * L_ * D_;    // [k][d] bf16
  const unsigned short* vbase0 = Vt + (size_t)bh * D_ * L_; // [d][k] bf16

  // staging geometry (R11): 2x 16B chunks per thread per tensor
  int srow[2], sc0[2];
#pragma unroll
  for (int i = 0; i < 2; ++i) {
    int gi  = i * 256 + t;
    srow[i] = gi >> 3;
    sc0[i]  = (gi & 7) << 3;
  }

  // bpermute source-lane byte indices
  int srcA = (lr + 16 * (2 * (lg & 1))) << 2;
  int srcB = srcA + 64;
  bool hin = (lg & 2) != 0;

  uint4 kpre[2], vpre[2];

  // prologue: tile 0 -> LDS buf 0
#pragma unroll
  for (int i = 0; i < 2; ++i) {
    kpre[i] = *reinterpret_cast<const uint4*>(ktb + srow[i] * 64 + sc0[i]);
    vpre[i] = *reinterpret_cast<const uint4*>(vbase0 + (size_t)srow[i] * L_ + sc0[i]);
  }
#pragma unroll
  for (int i = 0; i < 2; ++i) {
    int sw = srow[i] * 64 + (sc0[i] ^ ((srow[i] & 7) << 3));
    *reinterpret_cast<uint4*>(&Kl[0][sw]) = kpre[i];
    *reinterpret_cast<uint4*>(&Vl[0][sw]) = vpre[i];
  }
  __syncthreads();

  for (int ki = 0; ki < 32; ++ki) {
    int cur = ki & 1;
    int k0  = ki * 64;

    // (1) bit-mask load FIRST: one uint2 = 64 mask bits for this lane's q-row
    uint2 mbits = *reinterpret_cast<const uint2*>(
        mbase + (size_t)(qrow0 + lr) * 64 + (k0 >> 5));

    // (2) next-tile staging loads (drain at ds_write after PV)
    if (ki + 1 < 32) {
      const unsigned short* ksrc = ktb + (size_t)(ki + 1) * 4096;
      const unsigned short* vsrc = vbase0 + k0 + 64;
#pragma unroll
      for (int i = 0; i < 2; ++i) {
        kpre[i] = *reinterpret_cast<const uint4*>(ksrc + srow[i] * 64 + sc0[i]);
        vpre[i] = *reinterpret_cast<const uint4*>(vsrc + (size_t)srow[i] * L_ + sc0[i]);
      }
    }

    // (3) S^T = K Q^T
    f32x4 s[4] = {};
#pragma unroll
    for (int ks = 0; ks < 2; ++ks) {
#pragma unroll
      for (int n = 0; n < 4; ++n) {
        int row = n * 16 + lr;
        int col = ks * 32 + lg * 8;
        short8 kf = *reinterpret_cast<const short8*>(&Kl[cur][row * 64 + (col ^ ((row & 7) << 3))]);
        s[n] = __builtin_amdgcn_mfma_f32_16x16x32_bf16(kf, qf[ks], s[n], 0, 0, 0);
      }
    }

    // (4) mask + sigmoid; attn f32x4 NT-store; pack P
    unsigned int c[4][2];
#pragma unroll
    for (int n = 0; n < 4; ++n) {
      unsigned int mw = (n & 2) ? mbits.y : mbits.x;
      unsigned int mn = mw >> ((n & 1) * 16 + lg * 4);
      f32x4 f;
#pragma unroll
      for (int r = 0; r < 4; ++r) {
        float sv = s[n][r];
        float e  = __builtin_amdgcn_exp2f(sv * -1.44269504f);
        float at = ((mn >> r) & 1u) ? __builtin_amdgcn_rcpf(1.0f + e) : 0.0f;
        f[r] = at;
      }
      __builtin_nontemporal_store(f, reinterpret_cast<f32x4*>(
          abase + (size_t)(qrow0 + lr) * L_ + k0 + n * 16 + lg * 4));
      c[n][0] = pkbf16(f[0], f[1]);
      c[n][1] = pkbf16(f[2], f[3]);
    }

    // (5) intra-wave repack via ds_bpermute
    short8 pf[2];
#pragma unroll
    for (int ks = 0; ks < 2; ++ks) {
      unsigned int wv[4];
#pragma unroll
      for (int i = 0; i < 4; ++i) {
        int idx = (i >> 1) ? srcB : srcA;
        int lo = __builtin_amdgcn_ds_bpermute(idx, (int)c[2 * ks][i & 1]);
        int hi = __builtin_amdgcn_ds_bpermute(idx, (int)c[2 * ks + 1][i & 1]);
        wv[i] = (unsigned int)(hin ? hi : lo);
      }
      uint4 u4 = {wv[0], wv[1], wv[2], wv[3]};
      pf[ks] = __builtin_bit_cast(short8, u4);
    }

    // (6) O += P V
#pragma unroll
    for (int ks = 0; ks < 2; ++ks) {
#pragma unroll
      for (int n2 = 0; n2 < 4; ++n2) {
        int row = n2 * 16 + lr;
        int col = ks * 32 + lg * 8;
        short8 vf = *reinterpret_cast<const short8*>(&Vl[cur][row * 64 + (col ^ ((row & 7) << 3))]);
        o[n2] = __builtin_amdgcn_mfma_f32_16x16x32_bf16(pf[ks], vf, o[n2], 0, 0, 0);
      }
    }

    // (7) write next tile -> other LDS buffer
    if (ki + 1 < 32) {
#pragma unroll
      for (int i = 0; i < 2; ++i) {
        int sw = srow[i] * 64 + (sc0[i] ^ ((srow[i] & 7) << 3));
        *reinterpret_cast<uint4*>(&Kl[cur ^ 1][sw]) = kpre[i];
        *reinterpret_cast<uint4*>(&Vl[cur ^ 1][sw]) = vpre[i];
      }
    }
    __syncthreads();
  }

  // ---- epilogue: write O (nt) ----
  float* obase = O + ((size_t)bh * L_ + qrow0) * D_;
#pragma unroll
  for (int n2 = 0; n2 < 4; ++n2)
#pragma unroll
    for (int r = 0; r < 4; ++r)
      __builtin_nontemporal_store(o[n2][r],
          &obase[(lg * 4 + r) * D_ + n2 * 16 + lr]);
}

// ================= fallback path: R9 verbatim (needs 33.6 MB ws) =================
__global__ __launch_bounds__(256) void prep9_kernel(const float* __restrict__ V,
                                                    const int* __restrict__ M,
                                                    unsigned short* __restrict__ Vt,
                                                    unsigned char* __restrict__ M8) {
  __shared__ unsigned short lds[64 * 68];
  int bid = blockIdx.x;
  int t   = threadIdx.x;
  if (bid < NT) {
    int bh = bid >> 5;
    int kt = bid & 31;
    const float* vsrc = V + ((size_t)bh * L_ + (size_t)kt * 64) * D_;
#pragma unroll
    for (int i = 0; i < 4; ++i) {
      int f4  = i * 256 + t;
      int row = f4 >> 4;
      int c4  = (f4 & 15) << 2;
      float4 v = *reinterpret_cast<const float4*>(vsrc + row * D_ + c4);
      ushort4 u;
      u.x = (unsigned short)b16(v.x);
      u.y = (unsigned short)b16(v.y);
      u.z = (unsigned short)b16(v.z);
      u.w = (unsigned short)b16(v.w);
      *reinterpret_cast<ushort4*>(&lds[row * 68 + c4]) = u;
    }
    __syncthreads();
    unsigned short* dst = Vt + (size_t)bh * D_ * L_ + (size_t)kt * 64;
#pragma unroll
    for (int i = 0; i < 8; ++i) {
      int c  = i * 256 + t;
      int d  = c >> 5;
      int k2 = (c & 31) * 2;
      unsigned int lo = lds[(k2 + 0) * 68 + d];
      unsigned int hi = lds[(k2 + 1) * 68 + d];
      *reinterpret_cast<unsigned int*>(dst + d * L_ + k2) = lo | (hi << 16);
    }
  } else {
    int bid2 = bid - NT;
    const int* src = M + (size_t)bid2 * 8192;
    unsigned char* dst = M8 + (size_t)bid2 * 8192;
#pragma unroll
    for (int p = 0; p < 8; ++p) {
      int idx = (p * 256 + t) * 4;
      int4 v = *reinterpret_cast<const int4*>(src + idx);
      unsigned int pk = (v.x ? 1u : 0u) | (v.y ? 0x100u : 0u) |
                        (v.z ? 0x10000u : 0u) | (v.w ? 0x1000000u : 0u);
      *reinterpret_cast<unsigned int*>(dst + idx) = pk;
    }
  }
}

__global__ __launch_bounds__(256, 4) void attn9_kernel(
    const float* __restrict__ Q, const float* __restrict__ K,
    const unsigned char* __restrict__ M8, const unsigned short* __restrict__ Vt,
    float* __restrict__ O, float* __restrict__ A) {
  __shared__ unsigned short Kl[2][4096];
  __shared__ unsigned short Vl[2][4096];

  int wg  = blockIdx.x;
  int xcd = wg & 7;
  int j   = wg >> 3;
  int g   = xcd * 16 + (j & 15);
  int b   = g >> 5;
  int qt  = g & 31;
  int h   = j >> 4;
  int bh  = b * 16 + h;

  int t    = threadIdx.x;
  int lane = t & 63;
  int w    = t >> 6;
  int lr   = lane & 15;
  int lg   = lane >> 4;
  int qrow0 = qt * 64 + w * 16;

  short8 qf[2];
  {
    const float* qb = Q + ((size_t)bh * L_ + qrow0 + lr) * D_;
#pragma unroll
    for (int ks = 0; ks < 2; ++ks) {
      const float4* p = reinterpret_cast<const float4*>(qb + ks * 32 + lg * 8);
      float4 a = p[0], c = p[1];
      qf[ks] = (short8){b16(a.x * 0.125f), b16(a.y * 0.125f), b16(a.z * 0.125f), b16(a.w * 0.125f),
                        b16(c.x * 0.125f), b16(c.y * 0.125f), b16(c.z * 0.125f), b16(c.w * 0.125f)};
    }
  }

  f32x4 o[4] = {};
  const unsigned char* mbase = M8 + (size_t)b * L_ * L_;
  float* abase = A + (size_t)bh * L_ * L_;
  const float* kbase0 = K + (size_t)bh * L_ * D_;
  const unsigned short* vbase0 = Vt + (size_t)bh * D_ * L_;

  int krow[4], kc4[4];
#pragma unroll
  for (int i = 0; i < 4; ++i) {
    int f4  = i * 256 + t;
    krow[i] = f4 >> 4;
    kc4[i]  = (f4 & 15) << 2;
  }
  int vrow[2], vc0[2];
#pragma unroll
  for (int i = 0; i < 2; ++i) {
    int gi  = i * 256 + t;
    vrow[i] = gi >> 3;
    vc0[i]  = (gi & 7) << 3;
  }

  int srcA = (lr + 16 * (2 * (lg & 1))) << 2;
  int srcB = srcA + 64;
  bool hin = (lg & 2) != 0;

  float4 kreg[4];
  uint4  vreg[2];

#pragma unroll
  for (int i = 0; i < 4; ++i)
    kreg[i] = *reinterpret_cast<const float4*>(kbase0 + krow[i] * D_ + kc4[i]);
#pragma unroll
  for (int i = 0; i < 2; ++i)
    vreg[i] = *reinterpret_cast<const uint4*>(vbase0 + (size_t)vrow[i] * L_ + vc0[i]);
#pragma unroll
  for (int i = 0; i < 4; ++i) {
    ushort4 u;
    u.x = (unsigned short)b16(kreg[i].x);
    u.y = (unsigned short)b16(kreg[i].y);
    u.z = (unsigned short)b16(kreg[i].z);
    u.w = (unsigned short)b16(kreg[i].w);
    *reinterpret_cast<ushort4*>(&Kl[0][krow[i] * 64 + (kc4[i] ^ ((krow[i] & 7) << 3))]) = u;
  }
#pragma unroll
  for (int i = 0; i < 2; ++i)
    *reinterpret_cast<uint4*>(&Vl[0][vrow[i] * 64 + (vc0[i] ^ ((vrow[i] & 7) << 3))]) = vreg[i];
  __syncthreads();

  for (int ki = 0; ki < 32; ++ki) {
    int cur = ki & 1;
    int k0  = ki * 64;

    unsigned int mv[4];
#pragma unroll
    for (int n = 0; n < 4; ++n)
      mv[n] = *reinterpret_cast<const unsigned int*>(
          mbase + (size_t)(qrow0 + lr) * L_ + k0 + n * 16 + lg * 4);

    if (ki + 1 < 32) {
      const float* ksrc = kbase0 + (size_t)(k0 + 64) * D_;
      const unsigned short* vsrc = vbase0 + k0 + 64;
#pragma unroll
      for (int i = 0; i < 4; ++i)
        kreg[i] = *reinterpret_cast<const float4*>(ksrc + krow[i] * D_ + kc4[i]);
#pragma unroll
      for (int i = 0; i < 2; ++i)
        vreg[i] = *reinterpret_cast<const uint4*>(vsrc + (size_t)vrow[i] * L_ + vc0[i]);
    }

    f32x4 s[4] = {};
#pragma unroll
    for (int ks = 0; ks < 2; ++ks) {
#pragma unroll
      for (int n = 0; n < 4; ++n) {
        int row = n * 16 + lr;
        int col = ks * 32 + lg * 8;
        short8 kf = *reinterpret_cast<const short8*>(&Kl[cur][row * 64 + (col ^ ((row & 7) << 3))]);
        s[n] = __builtin_amdgcn_mfma_f32_16x16x32_bf16(kf, qf[ks], s[n], 0, 0, 0);
      }
    }

    unsigned int c[4][2];
#pragma unroll
    for (int n = 0; n < 4; ++n) {
      f32x4 f;
#pragma unroll
      for (int r = 0; r < 4; ++r) {
        float sv = s[n][r];
        float e  = __builtin_amdgcn_exp2f(sv * -1.44269504f);
        float at = ((mv[n] >> (8 * r)) & 0xFFu) ? __builtin_amdgcn_rcpf(1.0f + e) : 0.0f;
        f[r] = at;
      }
      __builtin_nontemporal_store(f, reinterpret_cast<f32x4*>(
          abase + (size_t)(qrow0 + lr) * L_ + k0 + n * 16 + lg * 4));
      c[n][0] = pkbf16(f[0], f[1]);
      c[n][1] = pkbf16(f[2], f[3]);
    }

    short8 pf[2];
#pragma unroll
    for (int ks = 0; ks < 2; ++ks) {
      unsigned int wv[4];
#pragma unroll
      for (int i = 0; i < 4; ++i) {
        int idx = (i >> 1) ? srcB : srcA;
        int lo = __builtin_amdgcn_ds_bpermute(idx, (int)c[2 * ks][i & 1]);
        int hi = __builtin_amdgcn_ds_bpermute(idx, (int)c[2 * ks + 1][i & 1]);
        wv[i] = (unsigned int)(hin ? hi : lo);
      }
      uint4 u4 = {wv[0], wv[1], wv[2], wv[3]};
      pf[ks] = __builtin_bit_cast(short8, u4);
    }

#pragma unroll
    for (int ks = 0; ks < 2; ++ks) {
#pragma unroll
      for (int n2 = 0; n2 < 4; ++n2) {
        int row = n2 * 16 + lr;
        int col = ks * 32 + lg * 8;
        short8 vf = *reinterpret_cast<const short8*>(&Vl[cur][row * 64 + (col ^ ((row & 7) << 3))]);
        o[n2] = __builtin_amdgcn_mfma_f32_16x16x32_bf16(pf[ks], vf, o[n2], 0, 0, 0);
      }
    }

    if (ki + 1 < 32) {
#pragma unroll
      for (int i = 0; i < 4; ++i) {
        ushort4 u;
        u.x = (unsigned short)b16(kreg[i].x);
        u.y = (unsigned short)b16(kreg[i].y);
        u.z = (unsigned short)b16(kreg[i].z);
        u.w = (unsigned short)b16(kreg[i].w);
        *reinterpret_cast<ushort4*>(&Kl[cur ^ 1][krow[i] * 64 + (kc4[i] ^ ((krow[i] & 7) << 3))]) = u;
      }
#pragma unroll
      for (int i = 0; i < 2; ++i)
        *reinterpret_cast<uint4*>(&Vl[cur ^ 1][vrow[i] * 64 + (vc0[i] ^ ((vrow[i] & 7) << 3))]) = vreg[i];
    }
    __syncthreads();
  }

  float* obase = O + ((size_t)bh * L_ + qrow0) * D_;
#pragma unroll
  for (int n2 = 0; n2 < 4; ++n2)
#pragma unroll
    for (int r = 0; r < 4; ++r)
      __builtin_nontemporal_store(o[n2][r],
          &obase[(lg * 4 + r) * D_ + n2 * 16 + lr]);
}

extern "C" void kernel_launch(void* const* d_in, const int* in_sizes, int n_in,
                              void* d_out, int out_size, void* d_ws, size_t ws_size,
                              hipStream_t stream) {
  (void)in_sizes; (void)n_in; (void)out_size;
  const float* Q = (const float*)d_in[0];
  const float* K = (const float*)d_in[1];
  const float* V = (const float*)d_in[2];
  const int*   M = (const int*)d_in[3];
  float* O = (float*)d_out;
  float* A = (float*)d_out + (size_t)BH * L_ * D_;

  const size_t mb_bytes = (size_t)B_ * L_ * 64 * 4;  // 2.1 MB bit mask
  if (ws_size >= 2 * TILE_BYTES + mb_bytes) {
    // Kt [0,16.8M), Vt [16.8,33.6M), Mb [33.6,35.7M)
    unsigned short* Kt = (unsigned short*)d_ws;
    unsigned short* Vt = (unsigned short*)((char*)d_ws + TILE_BYTES);
    unsigned int*   Mb = (unsigned int*)((char*)d_ws + 2 * TILE_BYTES);
    prep14_kernel<<<2 * NT + MB_, 256, 0, stream>>>(K, V, M, Kt, Vt, Mb);
    attn14_kernel<<<BH * 32, 256, 0, stream>>>(Q, Kt, Mb, Vt, O, A);
  } else {
    // proven R9 path
    unsigned short* Vt = (unsigned short*)d_ws;
    unsigned char*  M8 = (unsigned char*)d_ws + TILE_BYTES;
    prep9_kernel<<<NT + MB_, 256, 0, stream>>>(V, M, Vt, M8);
    attn9_kernel<<<BH * 32, 256, 0, stream>>>(Q, K, M8, Vt, O, A);
  }
}

// Round 16
// 281.740 us; speedup vs baseline: 1.1885x; 1.1885x over previous
//
#include <hip/hip_runtime.h>
#include <hip/hip_bf16.h>
#include <stdint.h>

#define B_ 4
#define H_ 16
#define L_ 2048
#define D_ 64
#define BH (B_ * H_)
#define NT (BH * 32)   // 64x64 tiles per tensor = 2048
#define MB_ 2048       // mask-pack blocks
#define TILE_BYTES ((size_t)NT * 4096 * 2)   // 16.8 MB per bf16 tensor image

typedef __attribute__((ext_vector_type(8))) short short8;
typedef __attribute__((ext_vector_type(4))) float f32x4;

__device__ __forceinline__ short b16(float f) {
  __hip_bfloat16 h = __float2bfloat16(f);
  return __builtin_bit_cast(short, h);
}
__device__ __forceinline__ unsigned int pkbf16(float lo, float hi) {
  return (unsigned int)(unsigned short)b16(lo) |
         ((unsigned int)(unsigned short)b16(hi) << 16);
}

// ================= prepass: K->bf16, V->transposed bf16, mask->bytes =================
__global__ __launch_bounds__(256) void prep10_kernel(const float* __restrict__ K,
                                                     const float* __restrict__ V,
                                                     const int* __restrict__ M,
                                                     unsigned short* __restrict__ Kt,
                                                     unsigned short* __restrict__ Vt,
                                                     unsigned char* __restrict__ M8) {
  __shared__ unsigned short lds[64 * 68];
  int bid = blockIdx.x;
  int t   = threadIdx.x;
  if (bid < NT) {
    const float* src = K + (size_t)bid * 4096;
    unsigned short* dst = Kt + (size_t)bid * 4096;
#pragma unroll
    for (int i = 0; i < 4; ++i) {
      int f4 = i * 256 + t;
      float4 v = *reinterpret_cast<const float4*>(src + f4 * 4);
      ushort4 u;
      u.x = (unsigned short)b16(v.x);
      u.y = (unsigned short)b16(v.y);
      u.z = (unsigned short)b16(v.z);
      u.w = (unsigned short)b16(v.w);
      *reinterpret_cast<ushort4*>(dst + f4 * 4) = u;
    }
  } else if (bid < 2 * NT) {
    bid -= NT;
    int bh = bid >> 5;
    int kt = bid & 31;
    const float* vsrc = V + ((size_t)bh * L_ + (size_t)kt * 64) * D_;
#pragma unroll
    for (int i = 0; i < 4; ++i) {
      int f4  = i * 256 + t;
      int row = f4 >> 4;
      int c4  = (f4 & 15) << 2;
      float4 v = *reinterpret_cast<const float4*>(vsrc + row * D_ + c4);
      ushort4 u;
      u.x = (unsigned short)b16(v.x);
      u.y = (unsigned short)b16(v.y);
      u.z = (unsigned short)b16(v.z);
      u.w = (unsigned short)b16(v.w);
      *reinterpret_cast<ushort4*>(&lds[row * 68 + c4]) = u;
    }
    __syncthreads();
    unsigned short* dst = Vt + (size_t)bh * D_ * L_ + (size_t)kt * 64;
#pragma unroll
    for (int i = 0; i < 8; ++i) {
      int c  = i * 256 + t;
      int d  = c >> 5;
      int k2 = (c & 31) * 2;
      unsigned int lo = lds[(k2 + 0) * 68 + d];
      unsigned int hi = lds[(k2 + 1) * 68 + d];
      *reinterpret_cast<unsigned int*>(dst + d * L_ + k2) = lo | (hi << 16);
    }
  } else {
    int bid2 = bid - 2 * NT;
    const int* src = M + (size_t)bid2 * 8192;
    unsigned char* dst = M8 + (size_t)bid2 * 8192;
#pragma unroll
    for (int p = 0; p < 8; ++p) {
      int idx = (p * 256 + t) * 4;
      int4 v = *reinterpret_cast<const int4*>(src + idx);
      unsigned int pk = (v.x ? 1u : 0u) | (v.y ? 0x100u : 0u) |
                        (v.z ? 0x10000u : 0u) | (v.w ? 0x1000000u : 0u);
      *reinterpret_cast<unsigned int*>(dst + idx) = pk;
    }
  }
}

// ================= attn: R11 champion (byte mask + all-bf16 staging) =================
__global__ __launch_bounds__(256, 4) void attn10_kernel(
    const float* __restrict__ Q, const unsigned short* __restrict__ Kt,
    const unsigned char* __restrict__ M8, const unsigned short* __restrict__ Vt,
    float* __restrict__ O, float* __restrict__ A) {
  __shared__ unsigned short Kl[2][4096];
  __shared__ unsigned short Vl[2][4096];

  int wg  = blockIdx.x;
  int xcd = wg & 7;
  int j   = wg >> 3;
  int g   = xcd * 16 + (j & 15);
  int b   = g >> 5;
  int qt  = g & 31;
  int h   = j >> 4;
  int bh  = b * 16 + h;

  int t    = threadIdx.x;
  int lane = t & 63;
  int w    = t >> 6;
  int lr   = lane & 15;
  int lg   = lane >> 4;
  int qrow0 = qt * 64 + w * 16;

  short8 qf[2];
  {
    const float* qb = Q + ((size_t)bh * L_ + qrow0 + lr) * D_;
#pragma unroll
    for (int ks = 0; ks < 2; ++ks) {
      const float4* p = reinterpret_cast<const float4*>(qb + ks * 32 + lg * 8);
      float4 a = p[0], c = p[1];
      qf[ks] = (short8){b16(a.x * 0.125f), b16(a.y * 0.125f), b16(a.z * 0.125f), b16(a.w * 0.125f),
                        b16(c.x * 0.125f), b16(c.y * 0.125f), b16(c.z * 0.125f), b16(c.w * 0.125f)};
    }
  }

  f32x4 o[4] = {};
  const unsigned char* mbase = M8 + (size_t)b * L_ * L_;
  float* abase = A + (size_t)bh * L_ * L_;
  const unsigned short* ktb = Kt + (size_t)bh * L_ * D_;
  const unsigned short* vbase0 = Vt + (size_t)bh * D_ * L_;

  int srow[2], sc0[2];
#pragma unroll
  for (int i = 0; i < 2; ++i) {
    int gi  = i * 256 + t;
    srow[i] = gi >> 3;
    sc0[i]  = (gi & 7) << 3;
  }

  int srcA = (lr + 16 * (2 * (lg & 1))) << 2;
  int srcB = srcA + 64;
  bool hin = (lg & 2) != 0;

  uint4 kpre[2], vpre[2];

#pragma unroll
  for (int i = 0; i < 2; ++i) {
    kpre[i] = *reinterpret_cast<const uint4*>(ktb + srow[i] * 64 + sc0[i]);
    vpre[i] = *reinterpret_cast<const uint4*>(vbase0 + (size_t)srow[i] * L_ + sc0[i]);
  }
#pragma unroll
  for (int i = 0; i < 2; ++i) {
    int sw = srow[i] * 64 + (sc0[i] ^ ((srow[i] & 7) << 3));
    *reinterpret_cast<uint4*>(&Kl[0][sw]) = kpre[i];
    *reinterpret_cast<uint4*>(&Vl[0][sw]) = vpre[i];
  }
  __syncthreads();

  for (int ki = 0; ki < 32; ++ki) {
    int cur = ki & 1;
    int k0  = ki * 64;

    // (1) byte-mask loads FIRST
    unsigned int mv[4];
#pragma unroll
    for (int n = 0; n < 4; ++n)
      mv[n] = *reinterpret_cast<const unsigned int*>(
          mbase + (size_t)(qrow0 + lr) * L_ + k0 + n * 16 + lg * 4);

    // (2) next-tile staging loads (drain at ds_write after PV)
    if (ki + 1 < 32) {
      const unsigned short* ksrc = ktb + (size_t)(ki + 1) * 4096;
      const unsigned short* vsrc = vbase0 + k0 + 64;
#pragma unroll
      for (int i = 0; i < 2; ++i) {
        kpre[i] = *reinterpret_cast<const uint4*>(ksrc + srow[i] * 64 + sc0[i]);
        vpre[i] = *reinterpret_cast<const uint4*>(vsrc + (size_t)srow[i] * L_ + sc0[i]);
      }
    }

    // (3) S^T = K Q^T
    f32x4 s[4] = {};
#pragma unroll
    for (int ks = 0; ks < 2; ++ks) {
#pragma unroll
      for (int n = 0; n < 4; ++n) {
        int row = n * 16 + lr;
        int col = ks * 32 + lg * 8;
        short8 kf = *reinterpret_cast<const short8*>(&Kl[cur][row * 64 + (col ^ ((row & 7) << 3))]);
        s[n] = __builtin_amdgcn_mfma_f32_16x16x32_bf16(kf, qf[ks], s[n], 0, 0, 0);
      }
    }

    // (4) mask + sigmoid; attn f32x4 NT-store; pack P
    unsigned int c[4][2];
#pragma unroll
    for (int n = 0; n < 4; ++n) {
      f32x4 f;
#pragma unroll
      for (int r = 0; r < 4; ++r) {
        float sv = s[n][r];
        float e  = __builtin_amdgcn_exp2f(sv * -1.44269504f);
        float at = ((mv[n] >> (8 * r)) & 0xFFu) ? __builtin_amdgcn_rcpf(1.0f + e) : 0.0f;
        f[r] = at;
      }
      __builtin_nontemporal_store(f, reinterpret_cast<f32x4*>(
          abase + (size_t)(qrow0 + lr) * L_ + k0 + n * 16 + lg * 4));
      c[n][0] = pkbf16(f[0], f[1]);
      c[n][1] = pkbf16(f[2], f[3]);
    }

    // (5) intra-wave repack via ds_bpermute
    short8 pf[2];
#pragma unroll
    for (int ks = 0; ks < 2; ++ks) {
      unsigned int wv[4];
#pragma unroll
      for (int i = 0; i < 4; ++i) {
        int idx = (i >> 1) ? srcB : srcA;
        int lo = __builtin_amdgcn_ds_bpermute(idx, (int)c[2 * ks][i & 1]);
        int hi = __builtin_amdgcn_ds_bpermute(idx, (int)c[2 * ks + 1][i & 1]);
        wv[i] = (unsigned int)(hin ? hi : lo);
      }
      uint4 u4 = {wv[0], wv[1], wv[2], wv[3]};
      pf[ks] = __builtin_bit_cast(short8, u4);
    }

    // (6) O += P V
#pragma unroll
    for (int ks = 0; ks < 2; ++ks) {
#pragma unroll
      for (int n2 = 0; n2 < 4; ++n2) {
        int row = n2 * 16 + lr;
        int col = ks * 32 + lg * 8;
        short8 vf = *reinterpret_cast<const short8*>(&Vl[cur][row * 64 + (col ^ ((row & 7) << 3))]);
        o[n2] = __builtin_amdgcn_mfma_f32_16x16x32_bf16(pf[ks], vf, o[n2], 0, 0, 0);
      }
    }

    // (7) write next tile -> other LDS buffer
    if (ki + 1 < 32) {
#pragma unroll
      for (int i = 0; i < 2; ++i) {
        int sw = srow[i] * 64 + (sc0[i] ^ ((srow[i] & 7) << 3));
        *reinterpret_cast<uint4*>(&Kl[cur ^ 1][sw]) = kpre[i];
        *reinterpret_cast<uint4*>(&Vl[cur ^ 1][sw]) = vpre[i];
      }
    }
    __syncthreads();
  }

  float* obase = O + ((size_t)bh * L_ + qrow0) * D_;
#pragma unroll
  for (int n2 = 0; n2 < 4; ++n2)
#pragma unroll
    for (int r = 0; r < 4; ++r)
      __builtin_nontemporal_store(o[n2][r],
          &obase[(lg * 4 + r) * D_ + n2 * 16 + lr]);
}

// ================= fallback path: R9 verbatim (needs 33.6 MB ws) =================
__global__ __launch_bounds__(256) void prep9_kernel(const float* __restrict__ V,
                                                    const int* __restrict__ M,
                                                    unsigned short* __restrict__ Vt,
                                                    unsigned char* __restrict__ M8) {
  __shared__ unsigned short lds[64 * 68];
  int bid = blockIdx.x;
  int t   = threadIdx.x;
  if (bid < NT) {
    int bh = bid >> 5;
    int kt = bid & 31;
    const float* vsrc = V + ((size_t)bh * L_ + (size_t)kt * 64) * D_;
#pragma unroll
    for (int i = 0; i < 4; ++i) {
      int f4  = i * 256 + t;
      int row = f4 >> 4;
      int c4  = (f4 & 15) << 2;
      float4 v = *reinterpret_cast<const float4*>(vsrc + row * D_ + c4);
      ushort4 u;
      u.x = (unsigned short)b16(v.x);
      u.y = (unsigned short)b16(v.y);
      u.z = (unsigned short)b16(v.z);
      u.w = (unsigned short)b16(v.w);
      *reinterpret_cast<ushort4*>(&lds[row * 68 + c4]) = u;
    }
    __syncthreads();
    unsigned short* dst = Vt + (size_t)bh * D_ * L_ + (size_t)kt * 64;
#pragma unroll
    for (int i = 0; i < 8; ++i) {
      int c  = i * 256 + t;
      int d  = c >> 5;
      int k2 = (c & 31) * 2;
      unsigned int lo = lds[(k2 + 0) * 68 + d];
      unsigned int hi = lds[(k2 + 1) * 68 + d];
      *reinterpret_cast<unsigned int*>(dst + d * L_ + k2) = lo | (hi << 16);
    }
  } else {
    int bid2 = bid - NT;
    const int* src = M + (size_t)bid2 * 8192;
    unsigned char* dst = M8 + (size_t)bid2 * 8192;
#pragma unroll
    for (int p = 0; p < 8; ++p) {
      int idx = (p * 256 + t) * 4;
      int4 v = *reinterpret_cast<const int4*>(src + idx);
      unsigned int pk = (v.x ? 1u : 0u) | (v.y ? 0x100u : 0u) |
                        (v.z ? 0x10000u : 0u) | (v.w ? 0x1000000u : 0u);
      *reinterpret_cast<unsigned int*>(dst + idx) = pk;
    }
  }
}

__global__ __launch_bounds__(256, 4) void attn9_kernel(
    const float* __restrict__ Q, const float* __restrict__ K,
    const unsigned char* __restrict__ M8, const unsigned short* __restrict__ Vt,
    float* __restrict__ O, float* __restrict__ A) {
  __shared__ unsigned short Kl[2][4096];
  __shared__ unsigned short Vl[2][4096];

  int wg  = blockIdx.x;
  int xcd = wg & 7;
  int j   = wg >> 3;
  int g   = xcd * 16 + (j & 15);
  int b   = g >> 5;
  int qt  = g & 31;
  int h   = j >> 4;
  int bh  = b * 16 + h;

  int t    = threadIdx.x;
  int lane = t & 63;
  int w    = t >> 6;
  int lr   = lane & 15;
  int lg   = lane >> 4;
  int qrow0 = qt * 64 + w * 16;

  short8 qf[2];
  {
    const float* qb = Q + ((size_t)bh * L_ + qrow0 + lr) * D_;
#pragma unroll
    for (int ks = 0; ks < 2; ++ks) {
      const float4* p = reinterpret_cast<const float4*>(qb + ks * 32 + lg * 8);
      float4 a = p[0], c = p[1];
      qf[ks] = (short8){b16(a.x * 0.125f), b16(a.y * 0.125f), b16(a.z * 0.125f), b16(a.w * 0.125f),
                        b16(c.x * 0.125f), b16(c.y * 0.125f), b16(c.z * 0.125f), b16(c.w * 0.125f)};
    }
  }

  f32x4 o[4] = {};
  const unsigned char* mbase = M8 + (size_t)b * L_ * L_;
  float* abase = A + (size_t)bh * L_ * L_;
  const float* kbase0 = K + (size_t)bh * L_ * D_;
  const unsigned short* vbase0 = Vt + (size_t)bh * D_ * L_;

  int krow[4], kc4[4];
#pragma unroll
  for (int i = 0; i < 4; ++i) {
    int f4  = i * 256 + t;
    krow[i] = f4 >> 4;
    kc4[i]  = (f4 & 15) << 2;
  }
  int vrow[2], vc0[2];
#pragma unroll
  for (int i = 0; i < 2; ++i) {
    int gi  = i * 256 + t;
    vrow[i] = gi >> 3;
    vc0[i]  = (gi & 7) << 3;
  }

  int srcA = (lr + 16 * (2 * (lg & 1))) << 2;
  int srcB = srcA + 64;
  bool hin = (lg & 2) != 0;

  float4 kreg[4];
  uint4  vreg[2];

#pragma unroll
  for (int i = 0; i < 4; ++i)
    kreg[i] = *reinterpret_cast<const float4*>(kbase0 + krow[i] * D_ + kc4[i]);
#pragma unroll
  for (int i = 0; i < 2; ++i)
    vreg[i] = *reinterpret_cast<const uint4*>(vbase0 + (size_t)vrow[i] * L_ + vc0[i]);
#pragma unroll
  for (int i = 0; i < 4; ++i) {
    ushort4 u;
    u.x = (unsigned short)b16(kreg[i].x);
    u.y = (unsigned short)b16(kreg[i].y);
    u.z = (unsigned short)b16(kreg[i].z);
    u.w = (unsigned short)b16(kreg[i].w);
    *reinterpret_cast<ushort4*>(&Kl[0][krow[i] * 64 + (kc4[i] ^ ((krow[i] & 7) << 3))]) = u;
  }
#pragma unroll
  for (int i = 0; i < 2; ++i)
    *reinterpret_cast<uint4*>(&Vl[0][vrow[i] * 64 + (vc0[i] ^ ((vrow[i] & 7) << 3))]) = vreg[i];
  __syncthreads();

  for (int ki = 0; ki < 32; ++ki) {
    int cur = ki & 1;
    int k0  = ki * 64;

    unsigned int mv[4];
#pragma unroll
    for (int n = 0; n < 4; ++n)
      mv[n] = *reinterpret_cast<const unsigned int*>(
          mbase + (size_t)(qrow0 + lr) * L_ + k0 + n * 16 + lg * 4);

    if (ki + 1 < 32) {
      const float* ksrc = kbase0 + (size_t)(k0 + 64) * D_;
      const unsigned short* vsrc = vbase0 + k0 + 64;
#pragma unroll
      for (int i = 0; i < 4; ++i)
        kreg[i] = *reinterpret_cast<const float4*>(ksrc + krow[i] * D_ + kc4[i]);
#pragma unroll
      for (int i = 0; i < 2; ++i)
        vreg[i] = *reinterpret_cast<const uint4*>(vsrc + (size_t)vrow[i] * L_ + vc0[i]);
    }

    f32x4 s[4] = {};
#pragma unroll
    for (int ks = 0; ks < 2; ++ks) {
#pragma unroll
      for (int n = 0; n < 4; ++n) {
        int row = n * 16 + lr;
        int col = ks * 32 + lg * 8;
        short8 kf = *reinterpret_cast<const short8*>(&Kl[cur][row * 64 + (col ^ ((row & 7) << 3))]);
        s[n] = __builtin_amdgcn_mfma_f32_16x16x32_bf16(kf, qf[ks], s[n], 0, 0, 0);
      }
    }

    unsigned int c[4][2];
#pragma unroll
    for (int n = 0; n < 4; ++n) {
      f32x4 f;
#pragma unroll
      for (int r = 0; r < 4; ++r) {
        float sv = s[n][r];
        float e  = __builtin_amdgcn_exp2f(sv * -1.44269504f);
        float at = ((mv[n] >> (8 * r)) & 0xFFu) ? __builtin_amdgcn_rcpf(1.0f + e) : 0.0f;
        f[r] = at;
      }
      __builtin_nontemporal_store(f, reinterpret_cast<f32x4*>(
          abase + (size_t)(qrow0 + lr) * L_ + k0 + n * 16 + lg * 4));
      c[n][0] = pkbf16(f[0], f[1]);
      c[n][1] = pkbf16(f[2], f[3]);
    }

    short8 pf[2];
#pragma unroll
    for (int ks = 0; ks < 2; ++ks) {
      unsigned int wv[4];
#pragma unroll
      for (int i = 0; i < 4; ++i) {
        int idx = (i >> 1) ? srcB : srcA;
        int lo = __builtin_amdgcn_ds_bpermute(idx, (int)c[2 * ks][i & 1]);
        int hi = __builtin_amdgcn_ds_bpermute(idx, (int)c[2 * ks + 1][i & 1]);
        wv[i] = (unsigned int)(hin ? hi : lo);
      }
      uint4 u4 = {wv[0], wv[1], wv[2], wv[3]};
      pf[ks] = __builtin_bit_cast(short8, u4);
    }

#pragma unroll
    for (int ks = 0; ks < 2; ++ks) {
#pragma unroll
      for (int n2 = 0; n2 < 4; ++n2) {
        int row = n2 * 16 + lr;
        int col = ks * 32 + lg * 8;
        short8 vf = *reinterpret_cast<const short8*>(&Vl[cur][row * 64 + (col ^ ((row & 7) << 3))]);
        o[n2] = __builtin_amdgcn_mfma_f32_16x16x32_bf16(pf[ks], vf, o[n2], 0, 0, 0);
      }
    }

    if (ki + 1 < 32) {
#pragma unroll
      for (int i = 0; i < 4; ++i) {
        ushort4 u;
        u.x = (unsigned short)b16(kreg[i].x);
        u.y = (unsigned short)b16(kreg[i].y);
        u.z = (unsigned short)b16(kreg[i].z);
        u.w = (unsigned short)b16(kreg[i].w);
        *reinterpret_cast<ushort4*>(&Kl[cur ^ 1][krow[i] * 64 + (kc4[i] ^ ((krow[i] & 7) << 3))]) = u;
      }
#pragma unroll
      for (int i = 0; i < 2; ++i)
        *reinterpret_cast<uint4*>(&Vl[cur ^ 1][vrow[i] * 64 + (vc0[i] ^ ((vrow[i] & 7) << 3))]) = vreg[i];
    }
    __syncthreads();
  }

  float* obase = O + ((size_t)bh * L_ + qrow0) * D_;
#pragma unroll
  for (int n2 = 0; n2 < 4; ++n2)
#pragma unroll
    for (int r = 0; r < 4; ++r)
      __builtin_nontemporal_store(o[n2][r],
          &obase[(lg * 4 + r) * D_ + n2 * 16 + lr]);
}

extern "C" void kernel_launch(void* const* d_in, const int* in_sizes, int n_in,
                              void* d_out, int out_size, void* d_ws, size_t ws_size,
                              hipStream_t stream) {
  (void)in_sizes; (void)n_in; (void)out_size;
  const float* Q = (const float*)d_in[0];
  const float* K = (const float*)d_in[1];
  const float* V = (const float*)d_in[2];
  const int*   M = (const int*)d_in[3];
  float* O = (float*)d_out;
  float* A = (float*)d_out + (size_t)BH * L_ * D_;

  if (ws_size >= 3 * TILE_BYTES) {
    // Kt [0,16.8M), Vt [16.8,33.6M), M8 [33.6,50.4M)
    unsigned short* Kt = (unsigned short*)d_ws;
    unsigned short* Vt = (unsigned short*)((char*)d_ws + TILE_BYTES);
    unsigned char*  M8 = (unsigned char*)d_ws + 2 * TILE_BYTES;
    prep10_kernel<<<2 * NT + MB_, 256, 0, stream>>>(K, V, M, Kt, Vt, M8);
    attn10_kernel<<<BH * 32, 256, 0, stream>>>(Q, Kt, M8, Vt, O, A);
  } else {
    // proven R9 path
    unsigned short* Vt = (unsigned short*)d_ws;
    unsigned char*  M8 = (unsigned char*)d_ws + TILE_BYTES;
    prep9_kernel<<<NT + MB_, 256, 0, stream>>>(V, M, Vt, M8);
    attn9_kernel<<<BH * 32, 256, 0, stream>>>(Q, K, M8, Vt, O, A);
  }
}